// Round 1
// baseline (947.444 us; speedup 1.0000x reference)
//
#include <hip/hip_runtime.h>
#include <hip/hip_bf16.h>

// RBF-kernel attention, MI355X.  B=8, Q=K=4096, D=256, d=64.
// Outputs (concat fp32): out [8,4096,64] then attn [8,4096,4096].
// R4: barrier-free / LDS-free k_attn.
//  - swapped QK^T (mfma(K,Q^T), 16x16x32): lane owns one q-row's scores -> rowsum
//    is 2 shfl_xor; attn store is a per-lane float4 (k contiguous in regs).
//  - PV + Wo epilogue use mfma_f32_16x16x16f16: its B-frag layout
//    (B[k=quad*4+i][col=ln]) matches the swapped-QK output registers exactly,
//    so P feeds PV with 2 cvt_pkrtz per group - no shuffles, no LDS.
//  - 1-wave blocks (grid 2048), K register-prefetched 1 tile ahead, V loaded at
//    tile-top / consumed at tile-end; K/V stream from L2 (512KB/batch).
//  - nontemporal attn + zero stores (don't evict K/V from L2).
//  - mask baked into kcw (-inf for k>=valid) in k_proj.

typedef _Float16 HALF;
typedef HALF half8 __attribute__((ext_vector_type(8)));
typedef HALF half4 __attribute__((ext_vector_type(4)));
typedef __fp16 fp16x2 __attribute__((ext_vector_type(2)));
typedef float f32x4 __attribute__((ext_vector_type(4)));

#define MFMA32(a, b, c) __builtin_amdgcn_mfma_f32_16x16x32_f16((a), (b), (c), 0, 0, 0)
#define MFMA16x16(a, b, c) __builtin_amdgcn_mfma_f32_16x16x16f16((a), (b), (c), 0, 0, 0)

union Cv4 { HALF h[4]; uint2 u; };
union Cv8 { HALF h[8]; uint4 u; };
union PK4 { fp16x2 p2[2]; half4 v; };

// ---------------- kernel 0: W transposes -> f16 ----------------
__global__ __launch_bounds__(256) void k_prep(const float* __restrict__ Wq,
                                              const float* __restrict__ Wk,
                                              const float* __restrict__ Wv,
                                              const float* __restrict__ Wo,
                                              HALF* __restrict__ wt,
                                              HALF* __restrict__ wto) {
    int gid = blockIdx.x * 256 + threadIdx.x;   // 208*256 = 53248 exact
    if (gid < 49152) {
        int t = gid >> 14;
        int rem = gid & 16383;
        int n = rem >> 8, k = rem & 255;
        const float* W = (t == 0) ? Wq : ((t == 1) ? Wk : Wv);
        wt[gid] = (HALF)W[k * 64 + n];
    } else {
        int rem = gid - 49152;
        int n = rem >> 6, k = rem & 63;
        wto[rem] = (HALF)Wo[k * 64 + n];
    }
}

// ---------------- kernel 1: projections ----------------
// Emits q_h/k_h row-major f16, v transposed vt[b][dv][key] f16,
// kc[b][key] = -0.125*||k_row||^2 for valid keys, -inf for masked keys.
__global__ __launch_bounds__(256, 2) void k_proj(const float* __restrict__ qs,
                                                 const float* __restrict__ ks,
                                                 const float* __restrict__ vs,
                                                 const float* __restrict__ bq,
                                                 const float* __restrict__ bk,
                                                 const float* __restrict__ bv,
                                                 const int* __restrict__ vlen,
                                                 const HALF* __restrict__ wt,
                                                 HALF* __restrict__ qh,
                                                 HALF* __restrict__ kh,
                                                 HALF* __restrict__ vth,
                                                 float* __restrict__ kcw) {
    int bid = blockIdx.x;
    int t = bid >> 9;           // which projection
    int rem = bid & 511;
    int b = rem & 7, rt = rem >> 3;
    int m0 = rt * 64;
    const float* X    = (t == 0) ? qs : ((t == 1) ? ks : vs);
    const float* bias = (t == 0) ? bq : ((t == 1) ? bk : bv);
    int valid = vlen[b];

    __shared__ char smem[67584];
    HALF (*sW)[264]  = (HALF(*)[264])smem;             // 33792 B
    HALF (*sX)[264]  = (HALF(*)[264])(smem + 33792);   // 33792 B
    float (*sOut)[68] = (float(*)[68])(smem + 33792);  // overlaps sX

    int tid = threadIdx.x;
    int w = tid >> 6, lane = tid & 63, ln = lane & 15, quad = lane >> 4;

    const HALF* wsrc = wt + t * 16384;
#pragma unroll
    for (int s = 0; s < 8; ++s) {
        int flat = (s * 256 + tid) * 8;
        int r = flat >> 8, c = flat & 255;
        *(uint4*)&sW[r][c] = *(const uint4*)(wsrc + flat);
    }
    const float* xbase = X + ((size_t)(b * 4096 + m0)) * 256;
#pragma unroll
    for (int s = 0; s < 16; ++s) {
        int flat = (s * 256 + tid) * 4;
        int r = flat >> 8, c = flat & 255;
        float4 xv = *(const float4*)(xbase + flat);
        Cv4 cv; cv.h[0] = (HALF)xv.x; cv.h[1] = (HALF)xv.y;
        cv.h[2] = (HALF)xv.z; cv.h[3] = (HALF)xv.w;
        *(uint2*)&sX[r][c] = cv.u;
    }
    __syncthreads();

    f32x4 zero4 = {0.f, 0.f, 0.f, 0.f};
    f32x4 acc[4] = {zero4, zero4, zero4, zero4};
#pragma unroll
    for (int kb = 0; kb < 8; ++kb) {
        half8 a = *(half8*)&sX[w * 16 + ln][kb * 32 + quad * 8];
#pragma unroll
        for (int t4 = 0; t4 < 4; ++t4) {
            half8 bf = *(half8*)&sW[t4 * 16 + ln][kb * 32 + quad * 8];
            acc[t4] = MFMA32(a, bf, acc[t4]);
        }
    }
    __syncthreads();   // done reading sX; reuse as sOut

    float bias_v[4];
#pragma unroll
    for (int t4 = 0; t4 < 4; ++t4) bias_v[t4] = bias[t4 * 16 + ln];

    float rsq[4] = {0.f, 0.f, 0.f, 0.f};
#pragma unroll
    for (int t4 = 0; t4 < 4; ++t4) {
#pragma unroll
        for (int r = 0; r < 4; ++r) {
            float v = acc[t4][r] + bias_v[t4];
            rsq[r] += v * v;
            sOut[w * 16 + quad * 4 + r][t4 * 16 + ln] = v;
        }
    }
    if (t == 1) {
#pragma unroll
        for (int r = 0; r < 4; ++r) {
            float v = rsq[r];
#pragma unroll
            for (int off = 1; off < 16; off <<= 1) v += __shfl_xor(v, off);
            if (ln == 0) {
                int kidx = m0 + w * 16 + quad * 4 + r;
                kcw[b * 4096 + kidx] = (kidx < valid) ? -0.125f * v : -__builtin_inff();
            }
        }
    }
    __syncthreads();

    if (t < 2) {
        HALF* dst = ((t == 0) ? qh : kh) + ((size_t)(b * 4096 + m0)) * 64;
#pragma unroll
        for (int s = 0; s < 4; ++s) {
            int flat = (s * 256 + tid) * 4;
            int r = flat >> 6, c = flat & 63;
            float4 v = *(float4*)&sOut[r][c];
            Cv4 cv; cv.h[0] = (HALF)v.x; cv.h[1] = (HALF)v.y;
            cv.h[2] = (HALF)v.z; cv.h[3] = (HALF)v.w;
            *(uint2*)(dst + flat) = cv.u;
        }
    } else {
        HALF* dst = vth + (size_t)b * 64 * 4096 + m0;
#pragma unroll
        for (int s = 0; s < 2; ++s) {
            int dv = s * 32 + (tid >> 3);
            int kc = (tid & 7) * 8;
            Cv8 cv;
#pragma unroll
            for (int i = 0; i < 8; ++i) cv.h[i] = (HALF)sOut[kc + i][dv];
            *(uint4*)(dst + (size_t)dv * 4096 + kc) = cv.u;
        }
    }
}

// ---------------- kernel 2: barrier-free two-pass RBF attention ----------------
// 1 wave / block; wave owns 16 q-rows.  grid = 8 batches * 256 row-groups = 2048.
__global__ __launch_bounds__(64, 2) void k_attn(const HALF* __restrict__ qh,
                                                const HALF* __restrict__ kh,
                                                const HALF* __restrict__ vth,
                                                const float* __restrict__ kcw,
                                                const int* __restrict__ vlen,
                                                const HALF* __restrict__ wto,
                                                const float* __restrict__ bo,
                                                float* __restrict__ attn_out,
                                                float* __restrict__ out) {
    int bid = blockIdx.x;
    int rg  = bid >> 3;                      // 16-row group within batch (0..255)
    int b   = (bid & 7) ^ ((rg & 1) << 2);   // 2 batches per XCD: L2-fit + balance
    int m0  = rg * 16;
    int lane = threadIdx.x;
    int ln = lane & 15, quad = lane >> 4;
    int valid = vlen[b];
    int nvt = (valid + 63) >> 6;

    const HALF*  kb  = kh  + (size_t)b * 4096 * 64;
    const HALF*  vtb = vth + (size_t)b * 64 * 4096;
    const float* kcb = kcw + b * 4096;

    // Q fragments (B-operand of swapped QK^T): Q[q=ln][d = chunk*32 + quad*8 + i]
    const HALF* qrow = qh + ((size_t)(b * 4096 + m0 + ln)) * 64 + quad * 8;
    half8 qb0 = *(const half8*)qrow;
    half8 qb1 = *(const half8*)(qrow + 32);

    const HALF* kfb = kb + (size_t)ln * 64 + quad * 8;   // K A-frag base
    f32x4 zz = {0.f, 0.f, 0.f, 0.f};

    // ---- pass A: row sums (K register-prefetched one tile ahead) ----
    half8 ka[4][2];
#pragma unroll
    for (int t4 = 0; t4 < 4; ++t4) {
        ka[t4][0] = *(const half8*)(kfb + t4 * 1024);
        ka[t4][1] = *(const half8*)(kfb + t4 * 1024 + 32);
    }
    float rs = 0.f;
    for (int nt = 0; nt < nvt; ++nt) {
        f32x4 kcv[4];
        const float* kcp = kcb + (nt << 6) + quad * 4;
#pragma unroll
        for (int t4 = 0; t4 < 4; ++t4) kcv[t4] = *(const f32x4*)(kcp + t4 * 16);

        f32x4 acc[4];
#pragma unroll
        for (int t4 = 0; t4 < 4; ++t4) {
            acc[t4] = MFMA32(ka[t4][0], qb0, zz);
            acc[t4] = MFMA32(ka[t4][1], qb1, acc[t4]);
        }
        int n1 = (nt + 1 < nvt ? nt + 1 : nt) << 6;
        const HALF* kf = kfb + (size_t)n1 * 64;
#pragma unroll
        for (int t4 = 0; t4 < 4; ++t4) {
            ka[t4][0] = *(const half8*)(kf + t4 * 1024);
            ka[t4][1] = *(const half8*)(kf + t4 * 1024 + 32);
        }
#pragma unroll
        for (int t4 = 0; t4 < 4; ++t4) {
#pragma unroll
            for (int r = 0; r < 4; ++r)
                rs += __expf(fmaf(acc[t4][r], 0.25f, kcv[t4][r]));
        }
    }
    rs += __shfl_xor(rs, 16);
    rs += __shfl_xor(rs, 32);
    float inv = 1.0f / rs;

    // ---- pass B: recompute, normalize, store attn (nontemporal), PV ----
#pragma unroll
    for (int t4 = 0; t4 < 4; ++t4) {
        ka[t4][0] = *(const half8*)(kfb + t4 * 1024);
        ka[t4][1] = *(const half8*)(kfb + t4 * 1024 + 32);
    }
    f32x4 cacc[4] = {zz, zz, zz, zz};
    float* arow = attn_out + ((size_t)(b * 4096 + m0 + ln)) * 4096 + quad * 4;
    const HALF* vfb = vtb + (size_t)ln * 4096 + quad * 4;  // V^T A-frag base

    for (int nt = 0; nt < nvt; ++nt) {
        int n0 = nt << 6;
        f32x4 kcv[4];
        const float* kcp = kcb + n0 + quad * 4;
#pragma unroll
        for (int t4 = 0; t4 < 4; ++t4) kcv[t4] = *(const f32x4*)(kcp + t4 * 16);

        // V fragments for this tile (consumed at the end -> latency hidden)
        half4 va[4][4];
#pragma unroll
        for (int t4dv = 0; t4dv < 4; ++t4dv)
#pragma unroll
            for (int t4k = 0; t4k < 4; ++t4k)
                va[t4dv][t4k] = *(const half4*)(vfb + (size_t)t4dv * 65536 + n0 + t4k * 16);

        f32x4 acc[4];
#pragma unroll
        for (int t4 = 0; t4 < 4; ++t4) {
            acc[t4] = MFMA32(ka[t4][0], qb0, zz);
            acc[t4] = MFMA32(ka[t4][1], qb1, acc[t4]);
        }
        int n1 = (nt + 1 < nvt ? nt + 1 : nt) << 6;
        const HALF* kf = kfb + (size_t)n1 * 64;
#pragma unroll
        for (int t4 = 0; t4 < 4; ++t4) {
            ka[t4][0] = *(const half8*)(kf + t4 * 1024);
            ka[t4][1] = *(const half8*)(kf + t4 * 1024 + 32);
        }

        float p[4][4];
#pragma unroll
        for (int t4 = 0; t4 < 4; ++t4) {
#pragma unroll
            for (int r = 0; r < 4; ++r)
                p[t4][r] = __expf(fmaf(acc[t4][r], 0.25f, kcv[t4][r])) * inv;
            f32x4 st = {p[t4][0], p[t4][1], p[t4][2], p[t4][3]};
            __builtin_nontemporal_store(st, (f32x4*)(arow + n0 + t4 * 16));
        }
        half4 pb[4];
#pragma unroll
        for (int t4 = 0; t4 < 4; ++t4) {
            PK4 pk;
            pk.p2[0] = __builtin_amdgcn_cvt_pkrtz(p[t4][0], p[t4][1]);
            pk.p2[1] = __builtin_amdgcn_cvt_pkrtz(p[t4][2], p[t4][3]);
            pb[t4] = pk.v;
        }
#pragma unroll
        for (int t4dv = 0; t4dv < 4; ++t4dv)
#pragma unroll
            for (int t4k = 0; t4k < 4; ++t4k)
                cacc[t4dv] = MFMA16x16(va[t4dv][t4k], pb[t4k], cacc[t4dv]);
    }

    // ---- masked tiles: pure zero streams ----
    for (int nt = nvt; nt < 64; ++nt) {
#pragma unroll
        for (int t4 = 0; t4 < 4; ++t4)
            __builtin_nontemporal_store(zz, (f32x4*)(arow + (nt << 6) + t4 * 16));
    }

    // ---- fused epilogue: out = ctx @ Wo + bo (all in-register) ----
    half4 cb[4];
#pragma unroll
    for (int t4 = 0; t4 < 4; ++t4) {
        PK4 pk;
        pk.p2[0] = __builtin_amdgcn_cvt_pkrtz(cacc[t4][0], cacc[t4][1]);
        pk.p2[1] = __builtin_amdgcn_cvt_pkrtz(cacc[t4][2], cacc[t4][3]);
        cb[t4] = pk.v;
    }
    f32x4 oacc[4] = {zz, zz, zz, zz};
    const HALF* wfb = wto + ln * 64 + quad * 4;
#pragma unroll
    for (int t4o = 0; t4o < 4; ++t4o)
#pragma unroll
        for (int t4c = 0; t4c < 4; ++t4c) {
            half4 wa = *(const half4*)(wfb + t4o * 1024 + t4c * 16);
            oacc[t4o] = MFMA16x16(wa, cb[t4c], oacc[t4o]);
        }
    float* orow = out + ((size_t)(b * 4096 + m0 + ln)) * 64 + quad * 4;
#pragma unroll
    for (int t4o = 0; t4o < 4; ++t4o) {
        f32x4 bo4 = *(const f32x4*)(bo + t4o * 16 + quad * 4);
        f32x4 ov = oacc[t4o] + bo4;
        *(f32x4*)(orow + t4o * 16) = ov;
    }
}

// ---------------- launch ----------------
extern "C" void kernel_launch(void* const* d_in, const int* in_sizes, int n_in,
                              void* d_out, int out_size, void* d_ws, size_t ws_size,
                              hipStream_t stream) {
    const float* qs = (const float*)d_in[0];
    const float* ks = (const float*)d_in[1];
    const float* vs = (const float*)d_in[2];
    const int* vlen = (const int*)d_in[3];
    const float* Wq = (const float*)d_in[4];
    const float* bq = (const float*)d_in[5];
    const float* Wk = (const float*)d_in[6];
    const float* bk = (const float*)d_in[7];
    const float* Wv = (const float*)d_in[8];
    const float* bv = (const float*)d_in[9];
    const float* Wo = (const float*)d_in[10];
    const float* bo = (const float*)d_in[11];

    float* out  = (float*)d_out;            // [8,4096,64]
    float* attn = out + 2097152;            // [8,4096,4096]

    char* wsb = (char*)d_ws;
    HALF*  wt  = (HALF*)(wsb + 0);          //  98304 B : W^T f16 (q,k,v)
    HALF*  wto = (HALF*)(wsb + 98304);      //   8192 B : Wo^T f16
    HALF*  qh  = (HALF*)(wsb + 131072);     //   4 MB   : q f16 [b][m][64]
    HALF*  kh  = (HALF*)(wsb + 4325376);    //   4 MB   : k f16 [b][n][64]
    HALF*  vth = (HALF*)(wsb + 8519680);    //   4 MB   : v^T f16 [b][dv][n]
    float* kcw = (float*)(wsb + 12713984);  // 128 KB   : -0.125*||k||^2 (-inf masked)

    k_prep<<<208, 256, 0, stream>>>(Wq, Wk, Wv, Wo, wt, wto);
    k_proj<<<1536, 256, 0, stream>>>(qs, ks, vs, bq, bk, bv, vlen, wt, qh, kh, vth, kcw);
    k_attn<<<2048, 64, 0, stream>>>(qh, kh, vth, kcw, vlen, wto, bo, attn, out);
}